// Round 6
// baseline (537.239 us; speedup 1.0000x reference)
//
#include <hip/hip_runtime.h>
#include <math.h>
#include <float.h>
#include <limits.h>

#define N 8192
#define D 64
#define TOPK 32
#define TILE 128
#define CAP 1024      // fallback path: per-wave LDS candidate cap
#define SLOT 32       // per-(row,stripe) candidate slots (u16 cols)
#define CAPR 1024     // pass-3 per-row candidate list cap
#define MARGIN 0.75f  // sound double-dip bound for fp16 sq-distance error
#define SSTRIDE 8     // column sampling stride for the threshold pass
#define MS 1024       // sampled columns (N / SSTRIDE)

typedef _Float16 f16x8 __attribute__((ext_vector_type(8)));
typedef _Float16 f16x4v __attribute__((ext_vector_type(4)));
typedef __attribute__((ext_vector_type(4))) float f32x4;

// orderable-uint encoding of float: a > b  <=>  ford(a) > ford(b)
__device__ __forceinline__ unsigned ford(float f) {
    unsigned u = __float_as_uint(f);
    return u ^ ((u & 0x80000000u) ? 0xFFFFFFFFu : 0x80000000u);
}
__device__ __forceinline__ float finv(unsigned u) {
    unsigned b = (u & 0x80000000u) ? (u ^ 0x80000000u) : ~u;
    return __uint_as_float(b);
}

// ---------------------------------------------------------------------------
// Kernel 1: row norms (exact fp32) + fp16 conversion of X1, X2 (RNE).
// ---------------------------------------------------------------------------
__global__ __launch_bounds__(256) void prep_kernel(
    const float* __restrict__ X1, const float* __restrict__ X2,
    float* __restrict__ nrm,
    _Float16* __restrict__ X1f, _Float16* __restrict__ X2f)
{
    int id = blockIdx.x * blockDim.x + threadIdx.x;
    if (id >= 2 * N) return;
    const float* X = (id < N) ? X1 : X2;
    _Float16* H = (id < N) ? X1f : X2f;
    int r = (id < N) ? id : id - N;
    const float4* p = (const float4*)(X + (size_t)r * D);
    f16x4v* ph = (f16x4v*)(H + (size_t)r * D);
    float s = 0.f;
#pragma unroll
    for (int q = 0; q < D / 4; ++q) {
        float4 v = p[q];
        s += v.x * v.x + v.y * v.y + v.z * v.z + v.w * v.w;
        f16x4v h;
        h[0] = (_Float16)v.x; h[1] = (_Float16)v.y;
        h[2] = (_Float16)v.z; h[3] = (_Float16)v.w;
        ph[q] = h;
    }
    nrm[id] = s;
}

// ---------------------------------------------------------------------------
// LDS-staged MFMA core (verified r5). XOR swizzle (row&7)<<3 f16-units on
// both write and read. Fragment layout verified r3/r4.
// ---------------------------------------------------------------------------
#define MFMA16F(a, b, c) __builtin_amdgcn_mfma_f32_16x16x32_f16((a), (b), (c), 0, 0, 0)

__device__ __forceinline__ void stage_tile(
    const _Float16* __restrict__ gsrc, _Float16* __restrict__ lds, int t)
{
    const f16x8* g = (const f16x8*)gsrc;
#pragma unroll
    for (int it = 0; it < 4; ++it) {
        int idx = it * 256 + t;          // 16B chunk index, 0..1023
        int row = idx >> 3;              // 8 chunks per 64-f16 row
        int co  = (idx & 7) << 3;        // f16 col offset
        int sw  = co ^ ((row & 7) << 3); // T2 swizzle, 16B granule
        *(f16x8*)&lds[row * 64 + sw] = g[idx];
    }
}

// strided variant: LDS row `row` <- X2f row (srow0 + row) * SSTRIDE
__device__ __forceinline__ void stage_tile_strided(
    const _Float16* __restrict__ X2f, int srow0, _Float16* __restrict__ lds, int t)
{
#pragma unroll
    for (int it = 0; it < 4; ++it) {
        int idx = it * 256 + t;
        int row = idx >> 3;
        int co  = (idx & 7) << 3;
        int sw  = co ^ ((row & 7) << 3);
        *(f16x8*)&lds[row * 64 + sw] =
            *(const f16x8*)(X2f + (size_t)(srow0 + row) * SSTRIDE * D + co);
    }
}

__device__ __forceinline__ void mfma_core_lds(
    const _Float16* __restrict__ Asm, const _Float16* __restrict__ Bsm,
    int wr, int wc, int lane, f32x4 acc[4][4])
{
    const int l15 = lane & 15;
    const int lg8 = (lane >> 4) * 8;

    f16x8 ah[4][2];
#pragma unroll
    for (int mt = 0; mt < 4; ++mt) {
        int row = wr * 64 + mt * 16 + l15;
        int sw0 = (lg8)      ^ ((row & 7) << 3);
        int sw1 = (32 + lg8) ^ ((row & 7) << 3);
        ah[mt][0] = *(const f16x8*)&Asm[row * 64 + sw0];
        ah[mt][1] = *(const f16x8*)&Asm[row * 64 + sw1];
    }
#pragma unroll
    for (int nt = 0; nt < 4; ++nt) {
        int row = wc * 64 + nt * 16 + l15;
        int sw0 = (lg8)      ^ ((row & 7) << 3);
        int sw1 = (32 + lg8) ^ ((row & 7) << 3);
        f16x8 b0 = *(const f16x8*)&Bsm[row * 64 + sw0];
        f16x8 b1 = *(const f16x8*)&Bsm[row * 64 + sw1];
#pragma unroll
        for (int mt = 0; mt < 4; ++mt) {
            acc[mt][nt] = MFMA16F(ah[mt][0], b0, acc[mt][nt]);
            acc[mt][nt] = MFMA16F(ah[mt][1], b1, acc[mt][nt]);
        }
    }
}

// ---------------------------------------------------------------------------
// Kernel 2: SAMPLED threshold pass. Grid (MS/TILE=8, N/TILE=64). Each block:
// 128 rows x 128 sampled cols (stride 8). Emits per-(row, 16-sampled-col)
// sub-maxes of v_f16 -> tmax[row][bx*8 + wc*4 + nt]  (64 values/row total).
// Each sub-max is a genuine v_f16 value of the row (max over a 16-col subset)
// -> the 32-distinct-subsets soundness argument holds unchanged.
// ---------------------------------------------------------------------------
__global__ __launch_bounds__(256) void mfma_stmax_kernel(
    const _Float16* __restrict__ X1f, const _Float16* __restrict__ X2f,
    const float* __restrict__ nrm, float* __restrict__ tmax)
{
    __shared__ _Float16 Asm[TILE * D];   // 16 KB
    __shared__ _Float16 Bsm[TILE * D];   // 16 KB

    const int t = threadIdx.x;
    const int lane = t & 63, w = t >> 6;
    const int wr = w >> 1, wc = w & 1;
    const int row0 = blockIdx.y * TILE;
    const int scol0 = blockIdx.x * TILE;   // sampled-col base
    const int l15 = lane & 15, lg = lane >> 4;

    stage_tile(X1f + (size_t)row0 * D, Asm, t);
    stage_tile_strided(X2f, scol0, Bsm, t);
    __syncthreads();

    f32x4 acc[4][4];
#pragma unroll
    for (int mt = 0; mt < 4; ++mt)
#pragma unroll
        for (int nt = 0; nt < 4; ++nt)
            acc[mt][nt] = (f32x4){0.f, 0.f, 0.f, 0.f};

    mfma_core_lds(Asm, Bsm, wr, wc, lane, acc);

    float nb[4];
#pragma unroll
    for (int nt = 0; nt < 4; ++nt)
        nb[nt] = nrm[N + (size_t)(scol0 + wc * 64 + nt * 16 + l15) * SSTRIDE];

#pragma unroll
    for (int mt = 0; mt < 4; ++mt) {
        float vm[4][4];   // [reg][nt]
#pragma unroll
        for (int reg = 0; reg < 4; ++reg) {
            float na = nrm[row0 + wr * 64 + mt * 16 + lg * 4 + reg];
#pragma unroll
            for (int nt = 0; nt < 4; ++nt)
                vm[reg][nt] = -fmaxf(na + nb[nt] - 2.0f * acc[mt][nt][reg], 0.f);
        }
        // reduce each (reg,nt) over the 16 col-lanes (xor stays in 16-group)
#pragma unroll
        for (int off = 1; off < 16; off <<= 1)
#pragma unroll
            for (int reg = 0; reg < 4; ++reg)
#pragma unroll
                for (int nt = 0; nt < 4; ++nt)
                    vm[reg][nt] = fmaxf(vm[reg][nt], __shfl_xor(vm[reg][nt], off));
        if (l15 == 0) {
#pragma unroll
            for (int reg = 0; reg < 4; ++reg) {
                size_t rowi = row0 + wr * 64 + mt * 16 + lg * 4 + reg;
#pragma unroll
                for (int nt = 0; nt < 4; ++nt)
                    tmax[rowi * 64 + blockIdx.x * 8 + wc * 4 + nt] = vm[reg][nt];
            }
        }
    }
}

// ---------------------------------------------------------------------------
// Kernel 3: thr[row] = 32nd-largest sub-max - MARGIN (layout identical: 64
// values per row). Soundness: 32 distinct 16-col subsets each contribute an
// actual row value >= T  =>  v_f16-rank32 >= T; top-32 exact col x then has
// v_f16(x) >= T - 2e; MARGIN = 2e.
// ---------------------------------------------------------------------------
__global__ __launch_bounds__(256) void thr_kernel(
    const float* __restrict__ tmax, float* __restrict__ thr)
{
    const int t = threadIdx.x;
    const int w = t >> 6;
    const int lane = t & 63;
    const int r = blockIdx.x * 4 + w;

    float tm = tmax[(size_t)r * 64 + lane];
    unsigned km = ford(tm);
    int rk = 0;
#pragma unroll
    for (int l = 0; l < 64; ++l) {
        unsigned o = __shfl(km, l);
        rk += (o > km || (o == km && l < lane)) ? 1 : 0;
    }
    unsigned long long bm = __ballot(rk == 31);
    float tv = __shfl(tm, __ffsll(bm) - 1);
    if (lane == 0) thr[r] = tv - MARGIN;
}

// ---------------------------------------------------------------------------
// Kernel 4: fp16 MFMA GEMM pass 2 (unchanged from verified r5) — zero-fill
// the out tile (268 MB total), append survivors (v_f16 >= thr[row]) to
// deterministic per-(row,stripe) slots. LDS atomics only.
// ---------------------------------------------------------------------------
__global__ __launch_bounds__(256) void mfma_cand_kernel(
    const _Float16* __restrict__ X1f, const _Float16* __restrict__ X2f,
    const float* __restrict__ nrm, const float* __restrict__ thr,
    float* __restrict__ out, unsigned short* __restrict__ cand,
    int* __restrict__ cnt)
{
    __shared__ _Float16 Asm[TILE * D];           // 16 KB
    __shared__ _Float16 Bsm[TILE * D];           // 16 KB
    __shared__ unsigned short lbuf[128][SLOT];   // 8 KB
    __shared__ int lcnt[128];

    const int t = threadIdx.x;
    const int lane = t & 63, w = t >> 6;
    const int wr = w >> 1, wc = w & 1;
    const int row0 = blockIdx.y * TILE, col0 = blockIdx.x * TILE;
    const int l15 = lane & 15, lg = lane >> 4;

    if (t < 128) lcnt[t] = 0;
    stage_tile(X1f + (size_t)row0 * D, Asm, t);
    stage_tile(X2f + (size_t)col0 * D, Bsm, t);

    // zero-fill this block's 128x128 out tile: stores are independent of the
    // MFMAs, so they drain under the compute.
    const float4 zz = make_float4(0.f, 0.f, 0.f, 0.f);
#pragma unroll
    for (int p = 0; p < 16; ++p) {
        int lin = p * 256 + t;
        int rr = lin >> 5;            // 0..127
        int c4 = (lin & 31) << 2;     // 0..124
        *(float4*)(out + (size_t)(row0 + rr) * N + col0 + c4) = zz;
    }
    __syncthreads();

    f32x4 acc[4][4];
#pragma unroll
    for (int mt = 0; mt < 4; ++mt)
#pragma unroll
        for (int nt = 0; nt < 4; ++nt)
            acc[mt][nt] = (f32x4){0.f, 0.f, 0.f, 0.f};

    mfma_core_lds(Asm, Bsm, wr, wc, lane, acc);

    float nb[4];
#pragma unroll
    for (int nt = 0; nt < 4; ++nt) nb[nt] = nrm[N + col0 + wc * 64 + nt * 16 + l15];

#pragma unroll
    for (int mt = 0; mt < 4; ++mt) {
#pragma unroll
        for (int reg = 0; reg < 4; ++reg) {
            int lrow = wr * 64 + mt * 16 + lg * 4 + reg;   // 0..127
            float na = nrm[row0 + lrow];
            float th = thr[row0 + lrow];
#pragma unroll
            for (int nt = 0; nt < 4; ++nt) {
                float v = -fmaxf(na + nb[nt] - 2.0f * acc[mt][nt][reg], 0.f);
                if (v >= th) {
                    int p0 = atomicAdd(&lcnt[lrow], 1);
                    if (p0 < SLOT)
                        lbuf[lrow][p0] = (unsigned short)(wc * 64 + nt * 16 + l15);
                }
            }
        }
    }
    __syncthreads();

    if (t < 128) {
        int c = lcnt[t];
        size_t sidx = (size_t)(row0 + t) * 64 + blockIdx.x;
        cnt[sidx] = c;                        // raw count (overflow detectable)
        unsigned short* cg = cand + sidx * SLOT;
        int m = min(c, SLOT);
        for (int j = 0; j < m; ++j) cg[j] = lbuf[t][j];
    }
}

// ---------------------------------------------------------------------------
// Kernel 5: one wave per row. Gather candidate cols (prefix-sum placement,
// overflow stripe -> all 128 cols: sound), recompute EXACT fp32 distances,
// exact top-32 (same key/tie-break as proven path), sqrt+softmax, scatter.
// ---------------------------------------------------------------------------
__global__ __launch_bounds__(256) void exact_topk_kernel(
    const float* __restrict__ X1, const float* __restrict__ X2,
    const float* __restrict__ nrm,
    const unsigned short* __restrict__ cand, const int* __restrict__ cnt,
    float* __restrict__ out, float* __restrict__ score_out)
{
    __shared__ float x1r[4][D];                     // 4 x 256 B
    __shared__ unsigned short lst[4][CAPR];         // 4 x 2 KB
    __shared__ unsigned long long kl[4][CAPR];      // 4 x 8 KB

    const int t = threadIdx.x;
    const int w = t >> 6;
    const int lane = t & 63;
    const int r = blockIdx.x * 4 + w;

    x1r[w][lane] = X1[(size_t)r * D + lane];

    int c = cnt[(size_t)r * 64 + lane];
    int eff = (c > SLOT) ? 128 : c;        // overflow: take whole stripe
    int pre = eff;
#pragma unroll
    for (int o = 1; o < 64; o <<= 1) {
        int pv = __shfl_up(pre, o);
        if (lane >= o) pre += pv;
    }
    int off0 = pre - eff;
    int M = __shfl(pre, 63);
    if (M > CAPR) M = CAPR;

    const unsigned short* cg = cand + ((size_t)r * 64 + lane) * SLOT;
    for (int j = 0; j < eff; ++j) {
        int pos = off0 + j;
        if (pos < CAPR) {
            int colloc = (c > SLOT) ? j : (int)cg[j];
            lst[w][pos] = (unsigned short)(lane * 128 + colloc);
        }
    }
    __builtin_amdgcn_s_waitcnt(0xC07F);   // lgkmcnt(0): lst + x1r visible in-wave

    float na = nrm[r];
    for (int q = lane; q < M; q += 64) {
        int col = lst[w][q];
        const float4* xr = (const float4*)(X2 + (size_t)col * D);
        float dot = 0.f;
#pragma unroll
        for (int i = 0; i < D / 4; ++i) {
            float4 xv = xr[i];
            dot += x1r[w][4 * i + 0] * xv.x + x1r[w][4 * i + 1] * xv.y
                 + x1r[w][4 * i + 2] * xv.z + x1r[w][4 * i + 3] * xv.w;
        }
        float v = -fmaxf(na + nrm[N + col] - 2.0f * dot, 0.f);
        kl[w][q] = ((unsigned long long)ford(v) << 32) | (unsigned)(8191 - col);
    }
    __builtin_amdgcn_s_waitcnt(0xC07F);

    unsigned long long mykey = 0ull;
    for (int it = 0; it < TOPK; ++it) {
        unsigned long long b = 0ull; int bp = 0;
        for (int q = lane; q < M; q += 64) {
            unsigned long long kk = kl[w][q];
            if (kk > b) { b = kk; bp = q; }
        }
        for (int off = 32; off > 0; off >>= 1) {
            unsigned long long ob = __shfl_down(b, off);
            int op = __shfl_down(bp, off);
            if (ob > b) { b = ob; bp = op; }
        }
        unsigned long long b0 = __shfl(b, 0);
        int bp0 = __shfl(bp, 0);
        if (lane == it) { mykey = b0; kl[w][bp0] = 0ull; }
    }

    float myv = -FLT_MAX; int myj = 0;
    if (lane < TOPK && mykey != 0ull) {
        float sv = finv((unsigned)(mykey >> 32));   // exact -max(sq,0)
        myv = -sqrtf(-sv);
        myj = 8191 - (int)(mykey & 0xFFFFFFFFu);
    }
    float Mx = __shfl(myv, 0);
    float e = (lane < TOPK && mykey != 0ull) ? expf(myv - Mx) : 0.f;
    float Z = e;
    for (int off = 32; off > 0; off >>= 1) Z += __shfl_xor(Z, off);
    float s = e / Z;
    if (lane < TOPK && mykey != 0ull) {
        score_out[(size_t)r * TOPK + lane] = s;
        out[(size_t)r * N + myj] = s;    // zeros laid down by pass 2
    }
}

// ---------------------------------------------------------------------------
// FALLBACK path (workspace too small): r0 verified pipeline.
// ---------------------------------------------------------------------------
__global__ __launch_bounds__(256) void norms_kernel(
    const float* __restrict__ X1, const float* __restrict__ X2,
    float* __restrict__ nrm)
{
    int id = blockIdx.x * blockDim.x + threadIdx.x;
    if (id >= 2 * N) return;
    const float* X = (id < N) ? X1 : X2;
    int r = (id < N) ? id : id - N;
    const float4* p = (const float4*)(X + (size_t)r * D);
    float s = 0.f;
#pragma unroll
    for (int q = 0; q < D / 4; ++q) {
        float4 v = p[q];
        s += v.x * v.x + v.y * v.y + v.z * v.z + v.w * v.w;
    }
    nrm[id] = s;
}

__global__ __launch_bounds__(256, 2) void dist_kernel(
    const float* __restrict__ X1, const float* __restrict__ X2,
    const float* __restrict__ nrm, float* __restrict__ out,
    float* __restrict__ tmax, int have_tmax)
{
    __shared__ float As[D * TILE];
    __shared__ float Bs[D * TILE];

    const int t = threadIdx.x;
    const int row0 = blockIdx.y * TILE;
    const int col0 = blockIdx.x * TILE;

#pragma unroll
    for (int p = 0; p < 8; ++p) {
        int lin = p * 256 + t;
        int r   = lin >> 4;
        int d4  = (lin & 15) << 2;
        int g   = (d4 >> 2) & 7;
        int cb  = r ^ (g << 3);
        float4 a = *(const float4*)(X1 + (size_t)(row0 + r) * D + d4);
        As[(d4 + 0) * TILE + cb] = a.x;
        As[(d4 + 1) * TILE + cb] = a.y;
        As[(d4 + 2) * TILE + cb] = a.z;
        As[(d4 + 3) * TILE + cb] = a.w;
        float4 b = *(const float4*)(X2 + (size_t)(col0 + r) * D + d4);
        Bs[(d4 + 0) * TILE + cb] = b.x;
        Bs[(d4 + 1) * TILE + cb] = b.y;
        Bs[(d4 + 2) * TILE + cb] = b.z;
        Bs[(d4 + 3) * TILE + cb] = b.w;
    }
    __syncthreads();

    const int tx = t & 15;
    const int ty = t >> 4;
    float acc[8][8] = {};

#pragma unroll 8
    for (int k = 0; k < D; ++k) {
        int gk  = (k >> 2) & 7;
        int ab  = k * TILE + ((ty ^ gk) << 3);
        int bb0 = k * TILE + ((4 * tx) ^ (gk << 3));
        float4 a0 = *(const float4*)&As[ab];
        float4 a1 = *(const float4*)&As[ab + 4];
        float4 b0 = *(const float4*)&Bs[bb0];
        float4 b1 = *(const float4*)&Bs[bb0 + 64];
        float av[8] = {a0.x, a0.y, a0.z, a0.w, a1.x, a1.y, a1.z, a1.w};
        float bv[8] = {b0.x, b0.y, b0.z, b0.w, b1.x, b1.y, b1.z, b1.w};
#pragma unroll
        for (int i = 0; i < 8; ++i)
#pragma unroll
            for (int j = 0; j < 8; ++j)
                acc[i][j] += av[i] * bv[j];
    }

    float na[8], nb[8];
#pragma unroll
    for (int i = 0; i < 8; ++i) na[i] = nrm[row0 + 8 * ty + i];
#pragma unroll
    for (int q = 0; q < 4; ++q) {
        nb[q]     = nrm[N + col0 + 4 * tx + q];
        nb[4 + q] = nrm[N + col0 + 64 + 4 * tx + q];
    }

    float rmax[8];
#pragma unroll
    for (int i = 0; i < 8; ++i) rmax[i] = -FLT_MAX;

#pragma unroll
    for (int i = 0; i < 8; ++i) {
        float* po = out + (size_t)(row0 + 8 * ty + i) * N + col0 + 4 * tx;
        float4 o0, o1;
        float* f0 = (float*)&o0;
        float* f1 = (float*)&o1;
#pragma unroll
        for (int q = 0; q < 4; ++q) {
            float s0 = na[i] + nb[q] - 2.0f * acc[i][q];
            f0[q] = -fmaxf(s0, 0.0f);
            float s1 = na[i] + nb[4 + q] - 2.0f * acc[i][4 + q];
            f1[q] = -fmaxf(s1, 0.0f);
            rmax[i] = fmaxf(rmax[i], fmaxf(f0[q], f1[q]));
        }
        *(float4*)po        = o0;
        *(float4*)(po + 64) = o1;
    }

    if (have_tmax) {
#pragma unroll
        for (int i = 0; i < 8; ++i) {
            float mv = rmax[i];
            mv = fmaxf(mv, __shfl_down(mv, 8, 16));
            mv = fmaxf(mv, __shfl_down(mv, 4, 16));
            mv = fmaxf(mv, __shfl_down(mv, 2, 16));
            mv = fmaxf(mv, __shfl_down(mv, 1, 16));
            if (tx == 0)
                tmax[(size_t)(row0 + 8 * ty + i) * 64 + blockIdx.x] = mv;
        }
    }
}

__global__ __launch_bounds__(256) void topk_kernel(
    float* __restrict__ out, float* __restrict__ score_out,
    const float* __restrict__ tmax, int have_tmax)
{
    __shared__ unsigned long long candl[4][CAP];   // 32 KB
    __shared__ int scnt[4];

    const int t    = threadIdx.x;
    const int w    = t >> 6;
    const int lane = t & 63;
    const int r    = blockIdx.x * 4 + w;
    float* row = out + (size_t)r * N;
    const float4* row4 = (const float4*)row;

    float thr;
    float lm = -FLT_MAX;
    if (have_tmax) {
        float tm = tmax[(size_t)r * 64 + lane];
        unsigned km = ford(tm);
        int rk = 0;
#pragma unroll
        for (int l = 0; l < 64; ++l) {
            unsigned o = __shfl(km, l);
            rk += (o > km || (o == km && l < lane)) ? 1 : 0;
        }
        unsigned long long bm = __ballot(rk == 31);
        thr = __shfl(tm, __ffsll(bm) - 1);
    } else {
#pragma unroll 8
        for (int c = 0; c < 32; ++c) {
            float4 x = row4[c * 64 + lane];
            lm = fmaxf(lm, fmaxf(fmaxf(x.x, x.y), fmaxf(x.z, x.w)));
        }
        thr = lm;
        for (int off = 32; off > 0; off >>= 1)
            thr = fminf(thr, __shfl_xor(thr, off));
    }

    for (int attempt = 0; ; ++attempt) {
        if (lane == 0) scnt[w] = 0;
        __builtin_amdgcn_s_waitcnt(0xC07F);
        for (int c = 0; c < 32; ++c) {
            float4 x = row4[c * 64 + lane];
            float vs[4] = {x.x, x.y, x.z, x.w};
#pragma unroll
            for (int q = 0; q < 4; ++q) {
                float v = vs[q];
                lm = fmaxf(lm, v);
                if (v >= thr) {
                    int p = atomicAdd(&scnt[w], 1);
                    if (p < CAP) {
                        unsigned long long key =
                            ((unsigned long long)ford(v) << 32) |
                            (unsigned)(8191 - (4 * (c * 64 + lane) + q));
                        candl[w][p] = key;
                    }
                }
            }
        }
        __builtin_amdgcn_s_waitcnt(0xC07F);
        if (scnt[w] <= CAP || attempt == 1) break;
        unsigned kml = ford(lm);
        int rk2 = 0;
#pragma unroll
        for (int l = 0; l < 64; ++l) {
            unsigned o = __shfl(kml, l);
            rk2 += (o < kml || (o == kml && l < lane)) ? 1 : 0;
        }
        unsigned long long bm2 = __ballot(rk2 == 15);
        float t2 = __shfl(lm, __ffsll(bm2) - 1);
        thr = fmaxf(thr, t2);
    }
    const int n = min(scnt[w], CAP);

    unsigned long long mykey = 0ull;
    for (int it = 0; it < TOPK; ++it) {
        unsigned long long b = 0ull; int bp = 0;
        for (int q = lane; q < n; q += 64) {
            unsigned long long kk = candl[w][q];
            if (kk > b) { b = kk; bp = q; }
        }
        for (int off = 32; off > 0; off >>= 1) {
            unsigned long long ob = __shfl_down(b, off);
            int op = __shfl_down(bp, off);
            if (ob > b) { b = ob; bp = op; }
        }
        unsigned long long b0 = __shfl(b, 0);
        int bp0 = __shfl(bp, 0);
        if (lane == it) { mykey = b0; candl[w][bp0] = 0ull; }
    }

    float myv = 0.f; int myj = 0;
    if (lane < TOPK) {
        float sv = finv((unsigned)(mykey >> 32));
        myv = -sqrtf(-sv);
        myj = 8191 - (int)(mykey & 0xFFFFFFFFu);
    }
    float Mx = __shfl(myv, 0);
    float e = (lane < TOPK) ? expf(myv - Mx) : 0.f;
    float Z = e;
    for (int off = 32; off > 0; off >>= 1) Z += __shfl_xor(Z, off);
    float s = e / Z;
    if (lane < TOPK) score_out[(size_t)r * TOPK + lane] = s;

    const float4 zz = make_float4(0.f, 0.f, 0.f, 0.f);
#pragma unroll 8
    for (int c = 0; c < 32; ++c) ((float4*)row)[c * 64 + lane] = zz;
    __builtin_amdgcn_s_waitcnt(0x0F70);   // vmcnt(0)
    if (lane < TOPK) row[myj] = s;
}

// ---------------------------------------------------------------------------
extern "C" void kernel_launch(void* const* d_in, const int* in_sizes, int n_in,
                              void* d_out, int out_size, void* d_ws, size_t ws_size,
                              hipStream_t stream)
{
    const float* X1 = (const float*)d_in[0];
    const float* X2 = (const float*)d_in[1];
    float* out = (float*)d_out;
    float* score = out + (size_t)N * N;

    // MFMA-path workspace layout (all blocks 16B-aligned by construction):
    //   nrm  : 2N f32          (64 KB)
    //   tmax : N*64 f32        (2 MB)
    //   thr  : N f32           (32 KB)
    //   cnt  : N*64 i32        (2 MB)
    //   X1f/X2f : N*64 f16 each (1 MB each)
    //   cand : N*64*SLOT u16   (32 MB)
    char* base = (char*)d_ws;
    float* nrm  = (float*)base;
    float* tmax = nrm + 2 * N;
    float* thrv = tmax + (size_t)N * 64;
    int*   cnt  = (int*)(thrv + N);
    _Float16* X1f = (_Float16*)(cnt + (size_t)N * 64);
    _Float16* X2f = X1f + (size_t)N * D;
    unsigned short* cand = (unsigned short*)(X2f + (size_t)N * D);

    size_t need_new = (size_t)(2 * N + (size_t)N * 64 + N) * sizeof(float)
                    + (size_t)N * 64 * sizeof(int)
                    + 2 * (size_t)N * D * sizeof(_Float16)
                    + (size_t)N * 64 * SLOT * sizeof(unsigned short);
    size_t need_old = (size_t)(2 * N + (size_t)N * 64) * sizeof(float);

    if (ws_size >= need_new) {
        prep_kernel<<<(2 * N + 255) / 256, 256, 0, stream>>>(X1, X2, nrm, X1f, X2f);
        dim3 sgrid(MS / TILE, N / TILE);   // 8 x 64 — sampled threshold pass
        mfma_stmax_kernel<<<sgrid, 256, 0, stream>>>(X1f, X2f, nrm, tmax);
        thr_kernel<<<N / 4, 256, 0, stream>>>(tmax, thrv);
        dim3 grid(N / TILE, N / TILE);     // 64 x 64 — single full GEMM
        mfma_cand_kernel<<<grid, 256, 0, stream>>>(X1f, X2f, nrm, thrv, out, cand, cnt);
        exact_topk_kernel<<<N / 4, 256, 0, stream>>>(X1, X2, nrm, cand, cnt, out, score);
    } else {
        float* tmax_f = nrm + 2 * N;
        int have_tmax = (ws_size >= need_old) ? 1 : 0;
        norms_kernel<<<(2 * N + 255) / 256, 256, 0, stream>>>(X1, X2, nrm);
        dim3 grid(N / TILE, N / TILE);
        dist_kernel<<<grid, 256, 0, stream>>>(X1, X2, nrm, out, tmax_f, have_tmax);
        topk_kernel<<<N / 4, 256, 0, stream>>>(out, score, tmax_f, have_tmax);
    }
}

// Round 7
// 382.680 us; speedup vs baseline: 1.4039x; 1.4039x over previous
//
#include <hip/hip_runtime.h>
#include <math.h>
#include <float.h>
#include <limits.h>

#define N 8192
#define D 64
#define TOPK 32
#define TILE 128
#define CAP 1024      // fallback path: per-wave LDS candidate cap
#define CAP2 256      // fused path: per-row survivor cap (~45 expected, sound thr)
#define MARGIN 1.0f   // 2*(fp16 dot err 0.375 + f16 storage rounding 0.125)

typedef _Float16 f16x8 __attribute__((ext_vector_type(8)));
typedef _Float16 f16x4v __attribute__((ext_vector_type(4)));
typedef __attribute__((ext_vector_type(4))) float f32x4;

// orderable-uint encoding of float: a > b  <=>  ford(a) > ford(b)
__device__ __forceinline__ unsigned ford(float f) {
    unsigned u = __float_as_uint(f);
    return u ^ ((u & 0x80000000u) ? 0xFFFFFFFFu : 0x80000000u);
}
__device__ __forceinline__ float finv(unsigned u) {
    unsigned b = (u & 0x80000000u) ? (u ^ 0x80000000u) : ~u;
    return __uint_as_float(b);
}

// ---------------------------------------------------------------------------
// Kernel 1: row norms (exact fp32) + fp16 conversion of X1, X2 (RNE).
// ---------------------------------------------------------------------------
__global__ __launch_bounds__(256) void prep_kernel(
    const float* __restrict__ X1, const float* __restrict__ X2,
    float* __restrict__ nrm,
    _Float16* __restrict__ X1f, _Float16* __restrict__ X2f)
{
    int id = blockIdx.x * blockDim.x + threadIdx.x;
    if (id >= 2 * N) return;
    const float* X = (id < N) ? X1 : X2;
    _Float16* H = (id < N) ? X1f : X2f;
    int r = (id < N) ? id : id - N;
    const float4* p = (const float4*)(X + (size_t)r * D);
    f16x4v* ph = (f16x4v*)(H + (size_t)r * D);
    float s = 0.f;
#pragma unroll
    for (int q = 0; q < D / 4; ++q) {
        float4 v = p[q];
        s += v.x * v.x + v.y * v.y + v.z * v.z + v.w * v.w;
        f16x4v h;
        h[0] = (_Float16)v.x; h[1] = (_Float16)v.y;
        h[2] = (_Float16)v.z; h[3] = (_Float16)v.w;
        ph[q] = h;
    }
    nrm[id] = s;
}

// ---------------------------------------------------------------------------
// LDS-staged MFMA core (verified r5). XOR swizzle (row&7)<<3 f16-units on
// both write and read. Fragment layout verified r3/r4.
// ---------------------------------------------------------------------------
#define MFMA16F(a, b, c) __builtin_amdgcn_mfma_f32_16x16x32_f16((a), (b), (c), 0, 0, 0)

__device__ __forceinline__ void stage_tile(
    const _Float16* __restrict__ gsrc, _Float16* __restrict__ lds, int t)
{
    const f16x8* g = (const f16x8*)gsrc;
#pragma unroll
    for (int it = 0; it < 4; ++it) {
        int idx = it * 256 + t;          // 16B chunk index, 0..1023
        int row = idx >> 3;              // 8 chunks per 64-f16 row
        int co  = (idx & 7) << 3;        // f16 col offset
        int sw  = co ^ ((row & 7) << 3); // T2 swizzle, 16B granule
        *(f16x8*)&lds[row * 64 + sw] = g[idx];
    }
}

__device__ __forceinline__ void mfma_core_lds(
    const _Float16* __restrict__ Asm, const _Float16* __restrict__ Bsm,
    int wr, int wc, int lane, f32x4 acc[4][4])
{
    const int l15 = lane & 15;
    const int lg8 = (lane >> 4) * 8;

    f16x8 ah[4][2];
#pragma unroll
    for (int mt = 0; mt < 4; ++mt) {
        int row = wr * 64 + mt * 16 + l15;
        int sw0 = (lg8)      ^ ((row & 7) << 3);
        int sw1 = (32 + lg8) ^ ((row & 7) << 3);
        ah[mt][0] = *(const f16x8*)&Asm[row * 64 + sw0];
        ah[mt][1] = *(const f16x8*)&Asm[row * 64 + sw1];
    }
#pragma unroll
    for (int nt = 0; nt < 4; ++nt) {
        int row = wc * 64 + nt * 16 + l15;
        int sw0 = (lg8)      ^ ((row & 7) << 3);
        int sw1 = (32 + lg8) ^ ((row & 7) << 3);
        f16x8 b0 = *(const f16x8*)&Bsm[row * 64 + sw0];
        f16x8 b1 = *(const f16x8*)&Bsm[row * 64 + sw1];
#pragma unroll
        for (int mt = 0; mt < 4; ++mt) {
            acc[mt][nt] = MFMA16F(ah[mt][0], b0, acc[mt][nt]);
            acc[mt][nt] = MFMA16F(ah[mt][1], b1, acc[mt][nt]);
        }
    }
}

// ---------------------------------------------------------------------------
// Kernel 2: SINGLE full MFMA GEMM. Writes S (f16 distance proxies, 134 MB)
// via LDS repack (coalesced 16B stores) and emits per-(row,128-col-stripe)
// maxes of the STORED (rounded) values -> tmax[row][64]. smem is reused:
// first as A|B staging (16KB+16KB), then (after a barrier) as the 128x128
// f16 S-tile (32KB) — LDS stays 32KB -> occupancy preserved.
// ---------------------------------------------------------------------------
__global__ __launch_bounds__(256) void mfma_s_kernel(
    const _Float16* __restrict__ X1f, const _Float16* __restrict__ X2f,
    const float* __restrict__ nrm, _Float16* __restrict__ S,
    float* __restrict__ tmax)
{
    __shared__ _Float16 smem[TILE * TILE];   // 32 KB, dual-purpose
    __shared__ float red[128][2];

    _Float16* Asm = smem;                    // 16 KB
    _Float16* Bsm = smem + TILE * D;         // 16 KB

    const int t = threadIdx.x;
    const int lane = t & 63, w = t >> 6;
    const int wr = w >> 1, wc = w & 1;
    const int row0 = blockIdx.y * TILE, col0 = blockIdx.x * TILE;
    const int l15 = lane & 15, lg = lane >> 4;

    stage_tile(X1f + (size_t)row0 * D, Asm, t);
    stage_tile(X2f + (size_t)col0 * D, Bsm, t);
    __syncthreads();

    f32x4 acc[4][4];
#pragma unroll
    for (int mt = 0; mt < 4; ++mt)
#pragma unroll
        for (int nt = 0; nt < 4; ++nt)
            acc[mt][nt] = (f32x4){0.f, 0.f, 0.f, 0.f};

    mfma_core_lds(Asm, Bsm, wr, wc, lane, acc);

    float nb[4];
#pragma unroll
    for (int nt = 0; nt < 4; ++nt) nb[nt] = nrm[N + col0 + wc * 64 + nt * 16 + l15];

    __syncthreads();   // all fragment ds_reads done -> safe to overwrite smem

    float rmax[4][4];
#pragma unroll
    for (int mt = 0; mt < 4; ++mt) {
#pragma unroll
        for (int reg = 0; reg < 4; ++reg) {
            int lrow = wr * 64 + mt * 16 + lg * 4 + reg;   // 0..127
            float na = nrm[row0 + lrow];
            float rm = -FLT_MAX;
#pragma unroll
            for (int nt = 0; nt < 4; ++nt) {
                float v = -fmaxf(na + nb[nt] - 2.0f * acc[mt][nt][reg], 0.f);
                _Float16 h = (_Float16)v;
                smem[lrow * TILE + wc * 64 + nt * 16 + l15] = h;
                rm = fmaxf(rm, (float)h);   // max of STORED value (consistency)
            }
            rmax[mt][reg] = rm;
        }
    }
    __syncthreads();   // S-tile complete in LDS

    // coalesced 16B stores of the S-tile: 2048 chunks / 256 threads
#pragma unroll
    for (int it = 0; it < 8; ++it) {
        int idx = it * 256 + t;
        int row = idx >> 4;            // 16 chunks per 128-f16 row
        int c8  = (idx & 15) << 3;
        *(f16x8*)(S + (size_t)(row0 + row) * N + col0 + c8) =
            *(const f16x8*)&smem[row * TILE + c8];
    }

    // stripe-max epilogue (r5-proven shfl path)
#pragma unroll
    for (int off = 1; off < 16; off <<= 1)
#pragma unroll
        for (int mt = 0; mt < 4; ++mt)
#pragma unroll
            for (int reg = 0; reg < 4; ++reg)
                rmax[mt][reg] = fmaxf(rmax[mt][reg], __shfl_xor(rmax[mt][reg], off));

    if (l15 == 0) {
#pragma unroll
        for (int mt = 0; mt < 4; ++mt)
#pragma unroll
            for (int reg = 0; reg < 4; ++reg)
                red[wr * 64 + mt * 16 + lg * 4 + reg][wc] = rmax[mt][reg];
    }
    __syncthreads();
    if (t < 128)
        tmax[(size_t)(row0 + t) * 64 + blockIdx.x] = fmaxf(red[t][0], red[t][1]);
}

// ---------------------------------------------------------------------------
// Kernel 3: thr[row] = 32nd-largest stripe max - MARGIN. 32 distinct stripes
// each contribute a STORED value >= T => stored-rank32 >= T; any true top-32
// col x has v_stored(x) >= v_exact(x) - e >= exact-rank32 - e >=
// stored-rank32 - 2e >= T - MARGIN. Also guarantees >= 32 survivors.
// ---------------------------------------------------------------------------
__global__ __launch_bounds__(256) void thr_kernel(
    const float* __restrict__ tmax, float* __restrict__ thr)
{
    const int t = threadIdx.x;
    const int w = t >> 6;
    const int lane = t & 63;
    const int r = blockIdx.x * 4 + w;

    float tm = tmax[(size_t)r * 64 + lane];
    unsigned km = ford(tm);
    int rk = 0;
#pragma unroll
    for (int l = 0; l < 64; ++l) {
        unsigned o = __shfl(km, l);
        rk += (o > km || (o == km && l < lane)) ? 1 : 0;
    }
    unsigned long long bm = __ballot(rk == 31);
    float tv = __shfl(tm, __ffsll(bm) - 1);
    if (lane == 0) thr[r] = tv - MARGIN;
}

// ---------------------------------------------------------------------------
// Kernel 4: fused topk+zero+scatter. One wave per row: stream the f16 row of
// S (16 KB), compact survivors (v >= thr, ~45) into LDS, recompute EXACT
// fp32 distances for them (selection/tie-break identical to verified path),
// 32x wave-argmax, sqrt+softmax, zero the fp32 out row, scatter 32 scores.
// ---------------------------------------------------------------------------
__global__ __launch_bounds__(256) void fused_topk_kernel(
    const float* __restrict__ X1, const float* __restrict__ X2,
    const float* __restrict__ nrm, const float* __restrict__ thr,
    const _Float16* __restrict__ S, float* __restrict__ out,
    float* __restrict__ score_out)
{
    __shared__ float x1r[4][D];                   // 1 KB
    __shared__ unsigned short lst[4][CAP2];       // 2 KB
    __shared__ unsigned long long kl[4][CAP2];    // 8 KB
    __shared__ int scnt[4];

    const int t = threadIdx.x;
    const int w = t >> 6;
    const int lane = t & 63;
    const int r = blockIdx.x * 4 + w;

    x1r[w][lane] = X1[(size_t)r * D + lane];
    if (lane == 0) scnt[w] = 0;
    const float th = thr[r];
    __builtin_amdgcn_s_waitcnt(0xC07F);   // lgkmcnt(0)

    // survivor scan: 128 f16 values per lane, coalesced 16B reads
    const _Float16* Sr = S + (size_t)r * N;
#pragma unroll 4
    for (int c = 0; c < 16; ++c) {
        f16x8 h8 = *(const f16x8*)(Sr + (size_t)(c * 64 + lane) * 8);
#pragma unroll
        for (int q = 0; q < 8; ++q) {
            float v = (float)h8[q];
            if (v >= th) {
                int p = atomicAdd(&scnt[w], 1);
                if (p < CAP2)
                    lst[w][p] = (unsigned short)((c * 64 + lane) * 8 + q);
            }
        }
    }
    __builtin_amdgcn_s_waitcnt(0xC07F);
    const int n = min(scnt[w], CAP2);     // >= 32 guaranteed by thr soundness

    // exact fp32 recompute for survivors
    float na = nrm[r];
    for (int q = lane; q < n; q += 64) {
        int col = lst[w][q];
        const float4* xr = (const float4*)(X2 + (size_t)col * D);
        float dot = 0.f;
#pragma unroll
        for (int i = 0; i < D / 4; ++i) {
            float4 xv = xr[i];
            dot += x1r[w][4 * i + 0] * xv.x + x1r[w][4 * i + 1] * xv.y
                 + x1r[w][4 * i + 2] * xv.z + x1r[w][4 * i + 3] * xv.w;
        }
        float v = -fmaxf(na + nrm[N + col] - 2.0f * dot, 0.f);
        kl[w][q] = ((unsigned long long)ford(v) << 32) | (unsigned)(8191 - col);
    }
    __builtin_amdgcn_s_waitcnt(0xC07F);

    unsigned long long mykey = 0ull;
    for (int it = 0; it < TOPK; ++it) {
        unsigned long long b = 0ull; int bp = 0;
        for (int q = lane; q < n; q += 64) {
            unsigned long long kk = kl[w][q];
            if (kk > b) { b = kk; bp = q; }
        }
        for (int off = 32; off > 0; off >>= 1) {
            unsigned long long ob = __shfl_down(b, off);
            int op = __shfl_down(bp, off);
            if (ob > b) { b = ob; bp = op; }
        }
        unsigned long long b0 = __shfl(b, 0);
        int bp0 = __shfl(bp, 0);
        if (lane == it) { mykey = b0; kl[w][bp0] = 0ull; }
    }

    float myv = 0.f; int myj = 0;
    if (lane < TOPK) {
        float sv = finv((unsigned)(mykey >> 32));   // exact -max(sq,0)
        myv = -sqrtf(-sv);
        myj = 8191 - (int)(mykey & 0xFFFFFFFFu);
    }
    float Mx = __shfl(myv, 0);
    float e = (lane < TOPK) ? expf(myv - Mx) : 0.f;
    float Z = e;
    for (int off = 32; off > 0; off >>= 1) Z += __shfl_xor(Z, off);
    float s = e / Z;
    if (lane < TOPK) score_out[(size_t)r * TOPK + lane] = s;

    // zero the fp32 out row, then scatter (r0-proven)
    float* row = out + (size_t)r * N;
    const float4 zz = make_float4(0.f, 0.f, 0.f, 0.f);
#pragma unroll 8
    for (int c = 0; c < 32; ++c) ((float4*)row)[c * 64 + lane] = zz;
    __builtin_amdgcn_s_waitcnt(0x0F70);   // vmcnt(0): zeros before scatter
    if (lane < TOPK) row[myj] = s;
}

// ---------------------------------------------------------------------------
// FALLBACK path (workspace too small): r0 verified pipeline.
// ---------------------------------------------------------------------------
__global__ __launch_bounds__(256) void norms_kernel(
    const float* __restrict__ X1, const float* __restrict__ X2,
    float* __restrict__ nrm)
{
    int id = blockIdx.x * blockDim.x + threadIdx.x;
    if (id >= 2 * N) return;
    const float* X = (id < N) ? X1 : X2;
    int r = (id < N) ? id : id - N;
    const float4* p = (const float4*)(X + (size_t)r * D);
    float s = 0.f;
#pragma unroll
    for (int q = 0; q < D / 4; ++q) {
        float4 v = p[q];
        s += v.x * v.x + v.y * v.y + v.z * v.z + v.w * v.w;
    }
    nrm[id] = s;
}

__global__ __launch_bounds__(256, 2) void dist_kernel(
    const float* __restrict__ X1, const float* __restrict__ X2,
    const float* __restrict__ nrm, float* __restrict__ out,
    float* __restrict__ tmax, int have_tmax)
{
    __shared__ float As[D * TILE];
    __shared__ float Bs[D * TILE];

    const int t = threadIdx.x;
    const int row0 = blockIdx.y * TILE;
    const int col0 = blockIdx.x * TILE;

#pragma unroll
    for (int p = 0; p < 8; ++p) {
        int lin = p * 256 + t;
        int r   = lin >> 4;
        int d4  = (lin & 15) << 2;
        int g   = (d4 >> 2) & 7;
        int cb  = r ^ (g << 3);
        float4 a = *(const float4*)(X1 + (size_t)(row0 + r) * D + d4);
        As[(d4 + 0) * TILE + cb] = a.x;
        As[(d4 + 1) * TILE + cb] = a.y;
        As[(d4 + 2) * TILE + cb] = a.z;
        As[(d4 + 3) * TILE + cb] = a.w;
        float4 b = *(const float4*)(X2 + (size_t)(col0 + r) * D + d4);
        Bs[(d4 + 0) * TILE + cb] = b.x;
        Bs[(d4 + 1) * TILE + cb] = b.y;
        Bs[(d4 + 2) * TILE + cb] = b.z;
        Bs[(d4 + 3) * TILE + cb] = b.w;
    }
    __syncthreads();

    const int tx = t & 15;
    const int ty = t >> 4;
    float acc[8][8] = {};

#pragma unroll 8
    for (int k = 0; k < D; ++k) {
        int gk  = (k >> 2) & 7;
        int ab  = k * TILE + ((ty ^ gk) << 3);
        int bb0 = k * TILE + ((4 * tx) ^ (gk << 3));
        float4 a0 = *(const float4*)&As[ab];
        float4 a1 = *(const float4*)&As[ab + 4];
        float4 b0 = *(const float4*)&Bs[bb0];
        float4 b1 = *(const float4*)&Bs[bb0 + 64];
        float av[8] = {a0.x, a0.y, a0.z, a0.w, a1.x, a1.y, a1.z, a1.w};
        float bv[8] = {b0.x, b0.y, b0.z, b0.w, b1.x, b1.y, b1.z, b1.w};
#pragma unroll
        for (int i = 0; i < 8; ++i)
#pragma unroll
            for (int j = 0; j < 8; ++j)
                acc[i][j] += av[i] * bv[j];
    }

    float na[8], nb[8];
#pragma unroll
    for (int i = 0; i < 8; ++i) na[i] = nrm[row0 + 8 * ty + i];
#pragma unroll
    for (int q = 0; q < 4; ++q) {
        nb[q]     = nrm[N + col0 + 4 * tx + q];
        nb[4 + q] = nrm[N + col0 + 64 + 4 * tx + q];
    }

    float rmax[8];
#pragma unroll
    for (int i = 0; i < 8; ++i) rmax[i] = -FLT_MAX;

#pragma unroll
    for (int i = 0; i < 8; ++i) {
        float* po = out + (size_t)(row0 + 8 * ty + i) * N + col0 + 4 * tx;
        float4 o0, o1;
        float* f0 = (float*)&o0;
        float* f1 = (float*)&o1;
#pragma unroll
        for (int q = 0; q < 4; ++q) {
            float s0 = na[i] + nb[q] - 2.0f * acc[i][q];
            f0[q] = -fmaxf(s0, 0.0f);
            float s1 = na[i] + nb[4 + q] - 2.0f * acc[i][4 + q];
            f1[q] = -fmaxf(s1, 0.0f);
            rmax[i] = fmaxf(rmax[i], fmaxf(f0[q], f1[q]));
        }
        *(float4*)po        = o0;
        *(float4*)(po + 64) = o1;
    }

    if (have_tmax) {
#pragma unroll
        for (int i = 0; i < 8; ++i) {
            float mv = rmax[i];
            mv = fmaxf(mv, __shfl_down(mv, 8, 16));
            mv = fmaxf(mv, __shfl_down(mv, 4, 16));
            mv = fmaxf(mv, __shfl_down(mv, 2, 16));
            mv = fmaxf(mv, __shfl_down(mv, 1, 16));
            if (tx == 0)
                tmax[(size_t)(row0 + 8 * ty + i) * 64 + blockIdx.x] = mv;
        }
    }
}

__global__ __launch_bounds__(256) void topk_kernel(
    float* __restrict__ out, float* __restrict__ score_out,
    const float* __restrict__ tmax, int have_tmax)
{
    __shared__ unsigned long long candl[4][CAP];   // 32 KB
    __shared__ int scnt[4];

    const int t    = threadIdx.x;
    const int w    = t >> 6;
    const int lane = t & 63;
    const int r    = blockIdx.x * 4 + w;
    float* row = out + (size_t)r * N;
    const float4* row4 = (const float4*)row;

    float thr;
    float lm = -FLT_MAX;
    if (have_tmax) {
        float tm = tmax[(size_t)r * 64 + lane];
        unsigned km = ford(tm);
        int rk = 0;
#pragma unroll
        for (int l = 0; l < 64; ++l) {
            unsigned o = __shfl(km, l);
            rk += (o > km || (o == km && l < lane)) ? 1 : 0;
        }
        unsigned long long bm = __ballot(rk == 31);
        thr = __shfl(tm, __ffsll(bm) - 1);
    } else {
#pragma unroll 8
        for (int c = 0; c < 32; ++c) {
            float4 x = row4[c * 64 + lane];
            lm = fmaxf(lm, fmaxf(fmaxf(x.x, x.y), fmaxf(x.z, x.w)));
        }
        thr = lm;
        for (int off = 32; off > 0; off >>= 1)
            thr = fminf(thr, __shfl_xor(thr, off));
    }

    for (int attempt = 0; ; ++attempt) {
        if (lane == 0) scnt[w] = 0;
        __builtin_amdgcn_s_waitcnt(0xC07F);
        for (int c = 0; c < 32; ++c) {
            float4 x = row4[c * 64 + lane];
            float vs[4] = {x.x, x.y, x.z, x.w};
#pragma unroll
            for (int q = 0; q < 4; ++q) {
                float v = vs[q];
                lm = fmaxf(lm, v);
                if (v >= thr) {
                    int p = atomicAdd(&scnt[w], 1);
                    if (p < CAP) {
                        unsigned long long key =
                            ((unsigned long long)ford(v) << 32) |
                            (unsigned)(8191 - (4 * (c * 64 + lane) + q));
                        candl[w][p] = key;
                    }
                }
            }
        }
        __builtin_amdgcn_s_waitcnt(0xC07F);
        if (scnt[w] <= CAP || attempt == 1) break;
        unsigned kml = ford(lm);
        int rk2 = 0;
#pragma unroll
        for (int l = 0; l < 64; ++l) {
            unsigned o = __shfl(kml, l);
            rk2 += (o < kml || (o == kml && l < lane)) ? 1 : 0;
        }
        unsigned long long bm2 = __ballot(rk2 == 15);
        float t2 = __shfl(lm, __ffsll(bm2) - 1);
        thr = fmaxf(thr, t2);
    }
    const int n = min(scnt[w], CAP);

    unsigned long long mykey = 0ull;
    for (int it = 0; it < TOPK; ++it) {
        unsigned long long b = 0ull; int bp = 0;
        for (int q = lane; q < n; q += 64) {
            unsigned long long kk = candl[w][q];
            if (kk > b) { b = kk; bp = q; }
        }
        for (int off = 32; off > 0; off >>= 1) {
            unsigned long long ob = __shfl_down(b, off);
            int op = __shfl_down(bp, off);
            if (ob > b) { b = ob; bp = op; }
        }
        unsigned long long b0 = __shfl(b, 0);
        int bp0 = __shfl(bp, 0);
        if (lane == it) { mykey = b0; candl[w][bp0] = 0ull; }
    }

    float myv = 0.f; int myj = 0;
    if (lane < TOPK) {
        float sv = finv((unsigned)(mykey >> 32));
        myv = -sqrtf(-sv);
        myj = 8191 - (int)(mykey & 0xFFFFFFFFu);
    }
    float Mx = __shfl(myv, 0);
    float e = (lane < TOPK) ? expf(myv - Mx) : 0.f;
    float Z = e;
    for (int off = 32; off > 0; off >>= 1) Z += __shfl_xor(Z, off);
    float s = e / Z;
    if (lane < TOPK) score_out[(size_t)r * TOPK + lane] = s;

    const float4 zz = make_float4(0.f, 0.f, 0.f, 0.f);
#pragma unroll 8
    for (int c = 0; c < 32; ++c) ((float4*)row)[c * 64 + lane] = zz;
    __builtin_amdgcn_s_waitcnt(0x0F70);   // vmcnt(0)
    if (lane < TOPK) row[myj] = s;
}

// ---------------------------------------------------------------------------
extern "C" void kernel_launch(void* const* d_in, const int* in_sizes, int n_in,
                              void* d_out, int out_size, void* d_ws, size_t ws_size,
                              hipStream_t stream)
{
    const float* X1 = (const float*)d_in[0];
    const float* X2 = (const float*)d_in[1];
    float* out = (float*)d_out;
    float* score = out + (size_t)N * N;

    // fused-path workspace layout (16B-aligned by construction):
    //   nrm  : 2N f32          (64 KB)
    //   tmax : N*64 f32        (2 MB)
    //   thr  : N f32           (32 KB)
    //   X1f/X2f : N*64 f16     (1 MB each)
    //   S    : N*N f16         (134 MB)
    char* base = (char*)d_ws;
    float* nrm  = (float*)base;
    float* tmax = nrm + 2 * N;
    float* thrv = tmax + (size_t)N * 64;
    _Float16* X1f = (_Float16*)(thrv + N);
    _Float16* X2f = X1f + (size_t)N * D;
    _Float16* S   = X2f + (size_t)N * D;

    size_t need_new = (size_t)(2 * N + (size_t)N * 64 + N) * sizeof(float)
                    + 2 * (size_t)N * D * sizeof(_Float16)
                    + (size_t)N * N * sizeof(_Float16);
    size_t need_old = (size_t)(2 * N + (size_t)N * 64) * sizeof(float);

    if (ws_size >= need_new) {
        prep_kernel<<<(2 * N + 255) / 256, 256, 0, stream>>>(X1, X2, nrm, X1f, X2f);
        dim3 grid(N / TILE, N / TILE);   // 64 x 64 — the single full GEMM
        mfma_s_kernel<<<grid, 256, 0, stream>>>(X1f, X2f, nrm, S, tmax);
        thr_kernel<<<N / 4, 256, 0, stream>>>(tmax, thrv);
        fused_topk_kernel<<<N / 4, 256, 0, stream>>>(
            X1, X2, nrm, thrv, S, out, score);
    } else {
        float* tmax_f = nrm + 2 * N;
        int have_tmax = (ws_size >= need_old) ? 1 : 0;
        norms_kernel<<<(2 * N + 255) / 256, 256, 0, stream>>>(X1, X2, nrm);
        dim3 grid(N / TILE, N / TILE);
        dist_kernel<<<grid, 256, 0, stream>>>(X1, X2, nrm, out, tmax_f, have_tmax);
        topk_kernel<<<N / 4, 256, 0, stream>>>(out, score, tmax_f, have_tmax);
    }
}